// Round 4
// baseline (716.030 us; speedup 1.0000x reference)
//
#include <hip/hip_runtime.h>
#include <hip/hip_bf16.h>
#include <math.h>

// Problem constants
#define Bq 128
#define Nq 100
#define Dq 2048
#define Hq 1024
#define Oq 1600
#define Aq 400
#define Lq 2048
#define Mq (Bq * Nq)     // 12800 rows max
#define OqP 1664         // Oq padded to multiple of 128
#define AqP 512          // Aq padded to multiple of 128

typedef __attribute__((ext_vector_type(8))) short bf16x8;
typedef __attribute__((ext_vector_type(4))) float f32x4;
typedef __attribute__((ext_vector_type(16))) float f32x16;
typedef unsigned short ushort;

// ---------------- helpers ----------------
__device__ __forceinline__ void split1(float v, ushort& h, ushort& l) {
    __hip_bfloat16 bh = __float2bfloat16(v);          // RNE
    float fh = __bfloat162float(bh);
    __hip_bfloat16 bl = __float2bfloat16(v - fh);     // exact residual, then RNE
    h = __builtin_bit_cast(ushort, bh);
    l = __builtin_bit_cast(ushort, bl);
}

__device__ __forceinline__ void gl_lds16(const ushort* g, ushort* lds) {
    __builtin_amdgcn_global_load_lds(
        (const __attribute__((address_space(1))) unsigned int*)g,
        (__attribute__((address_space(3))) unsigned int*)lds,
        16, 0, 0);
}

// ------------- row compaction: offsets + rowmap -------------
__global__ void build_offsets(const int* __restrict__ num_descs,
                              int* __restrict__ off, int* __restrict__ mc,
                              int* __restrict__ rowmap)
{
    __shared__ int cnt[Bq];
    __shared__ int offs[Bq + 1];
    const int t = threadIdx.x;            // 0..127
    int nd = num_descs[t];
    nd = nd < 0 ? 0 : (nd > Nq ? Nq : nd);
    const int c = nd < 1 ? 1 : nd;
    cnt[t] = c;
    __syncthreads();
    if (t == 0) {
        int s = 0;
        for (int i = 0; i < Bq; i++) { offs[i] = s; s += cnt[i]; }
        offs[Bq] = s;
        mc[0] = s;                          // Mc
        mc[1] = (s + 127) & ~127;           // McPad
    }
    __syncthreads();
    off[t] = offs[t];
    for (int i = t; i < Mq; i += Bq) rowmap[i] = -1;
    __syncthreads();
    const int o = offs[t];
    for (int n = 0; n < c; n++) rowmap[o + n] = t * Nq + n;
}

// ---------------- gather + split x into compact hi/lo bf16 ----------------
__global__ void split_compact(const float* __restrict__ x,
                              const int* __restrict__ rowmap,
                              const int* __restrict__ mc,
                              ushort* __restrict__ hi, ushort* __restrict__ lo)
{
    const long i = ((long)blockIdx.x * blockDim.x + threadIdx.x) * 8;
    const int c = (int)(i >> 11);          // compact row (Dq=2048)
    if (c >= mc[1]) return;
    const int orig = (c < mc[0]) ? rowmap[c] : -1;
    ushort h[8], l[8];
    if (orig < 0) {
#pragma unroll
        for (int j = 0; j < 8; j++) { h[j] = 0; l[j] = 0; }
    } else {
        const float* src = x + (size_t)orig * Dq + (i & 2047);
        float4 v0 = *(const float4*)(src);
        float4 v1 = *(const float4*)(src + 4);
        float v[8] = {v0.x, v0.y, v0.z, v0.w, v1.x, v1.y, v1.z, v1.w};
#pragma unroll
        for (int j = 0; j < 8; j++) split1(v[j], h[j], l[j]);
    }
    *(bf16x8*)(hi + i) = *(bf16x8*)h;
    *(bf16x8*)(lo + i) = *(bf16x8*)l;
}

// ------- batched transpose+split: W[K][N] -> Wt_hi/lo[Npad][K], 6 segments -------
struct TSeg { const float* W; ushort* Th; ushort* Tl; int K; int N; int gx; int base; };
struct TSegs { TSeg s[6]; };

__global__ void tsplit_all(TSegs a)
{
    const int id = blockIdx.x;
    TSeg sg = a.s[5];
#pragma unroll
    for (int i = 4; i >= 0; i--) if (id < a.s[i + 1].base) sg = a.s[i];
    const int local = id - sg.base;
    const int bn = (local % sg.gx) * 32;
    const int bk = (local / sg.gx) * 32;

    __shared__ float t[32][33];
    const int tx = threadIdx.x & 31, ty = threadIdx.x >> 5;   // ty 0..7
#pragma unroll
    for (int i = 0; i < 4; i++) {
        const int k = bk + ty + i * 8, n = bn + tx;
        t[ty + i * 8][tx] = (n < sg.N) ? sg.W[(size_t)k * sg.N + n] : 0.f;
    }
    __syncthreads();
#pragma unroll
    for (int i = 0; i < 4; i++) {
        const int n = bn + ty + i * 8, k = bk + tx;
        const float v = t[tx][ty + i * 8];
        ushort h, l;
        split1(v, h, l);
        sg.Th[(size_t)n * sg.K + k] = h;
        sg.Tl[(size_t)n * sg.K + k] = l;
    }
}

// ---------------- split-bf16 MFMA GEMM (32x32x16, branch-fused via z) ----------------
struct GArgs {
    const ushort* Ah; const ushort* Al;     // A [McPad][lda] split
    const ushort* Bh; const ushort* Bl;     // B [Npad][K] split (transposed)
    const float* bias;
    float* Cf; ushort* Ch; ushort* Cl;      // outputs
    int K, Npad, Nreal, lda, ldc, mode;     // mode 1: relu+split write; 0: fp32 write
};

__global__ __launch_bounds__(256) void gemm_split(GArgs g0, GArgs g1,
                                                  const int* __restrict__ mcp)
{
    const GArgs g = (blockIdx.z == 0) ? g0 : g1;
    const int bm = blockIdx.y * 128;
    const int bn = blockIdx.x * 128;
    if (bn >= g.Npad) return;
    if (bm >= mcp[1]) return;

    __shared__ __align__(16) ushort sAh[128 * 32];
    __shared__ __align__(16) ushort sAl[128 * 32];
    __shared__ __align__(16) ushort sBh[128 * 32];
    __shared__ __align__(16) ushort sBl[128 * 32];

    const int tid  = threadIdx.x;
    const int wave = tid >> 6;           // 0..3
    const int lane = tid & 63;
    const int wm = (wave >> 1) * 64;     // wave's 64x64 quadrant
    const int wn = (wave & 1) * 64;
    const int l31  = lane & 31;
    const int half = lane >> 5;          // 0..1

    // staging: per wave, 2 instrs per buffer; instr q covers rows wave*32+q*16
    const int srow = wave * 32 + (lane >> 2);       // 0..127 (q=0 half)
    const int scol = (lane & 3) * 8;                // k element offset
    const ushort* gAh = g.Ah + (size_t)(bm + srow) * g.lda + scol;
    const ushort* gAl = g.Al + (size_t)(bm + srow) * g.lda + scol;
    const ushort* gBh = g.Bh + (size_t)(bn + srow) * g.K + scol;
    const ushort* gBl = g.Bl + (size_t)(bn + srow) * g.K + scol;
    const size_t rstepA = (size_t)16 * g.lda;
    const size_t rstepB = (size_t)16 * g.K;
    ushort* lAh0 = &sAh[(wave * 32) * 32];  ushort* lAh1 = &sAh[(wave * 32 + 16) * 32];
    ushort* lAl0 = &sAl[(wave * 32) * 32];  ushort* lAl1 = &sAl[(wave * 32 + 16) * 32];
    ushort* lBh0 = &sBh[(wave * 32) * 32];  ushort* lBh1 = &sBh[(wave * 32 + 16) * 32];
    ushort* lBl0 = &sBl[(wave * 32) * 32];  ushort* lBl1 = &sBl[(wave * 32 + 16) * 32];

    // fragment offsets: [kstep][tile] ; A rows wm+i*32, k = ks*16 + half*8
    int aoff[2][2], boff[2][2];
#pragma unroll
    for (int ks = 0; ks < 2; ks++)
#pragma unroll
        for (int i = 0; i < 2; i++) {
            aoff[ks][i] = (wm + i * 32 + l31) * 32 + ks * 16 + half * 8;
            boff[ks][i] = (wn + i * 32 + l31) * 32 + ks * 16 + half * 8;
        }

    f32x16 acc[2][2] = {};

    for (int k0 = 0; k0 < g.K; k0 += 32) {
        gl_lds16(gAh + k0, lAh0);  gl_lds16(gAh + rstepA + k0, lAh1);
        gl_lds16(gAl + k0, lAl0);  gl_lds16(gAl + rstepA + k0, lAl1);
        gl_lds16(gBh + k0, lBh0);  gl_lds16(gBh + rstepB + k0, lBh1);
        gl_lds16(gBl + k0, lBl0);  gl_lds16(gBl + rstepB + k0, lBl1);
        __syncthreads();

#pragma unroll
        for (int ks = 0; ks < 2; ks++) {
            bf16x8 ah[2], al[2], bh[2], bl[2];
#pragma unroll
            for (int i = 0; i < 2; i++) {
                ah[i] = *(const bf16x8*)&sAh[aoff[ks][i]];
                al[i] = *(const bf16x8*)&sAl[aoff[ks][i]];
                bh[i] = *(const bf16x8*)&sBh[boff[ks][i]];
                bl[i] = *(const bf16x8*)&sBl[boff[ks][i]];
            }
#pragma unroll
            for (int i = 0; i < 2; i++)
#pragma unroll
                for (int j = 0; j < 2; j++) {
                    acc[i][j] = __builtin_amdgcn_mfma_f32_32x32x16_bf16(ah[i], bh[j], acc[i][j], 0, 0, 0);
                    acc[i][j] = __builtin_amdgcn_mfma_f32_32x32x16_bf16(ah[i], bl[j], acc[i][j], 0, 0, 0);
                    acc[i][j] = __builtin_amdgcn_mfma_f32_32x32x16_bf16(al[i], bh[j], acc[i][j], 0, 0, 0);
                }
        }
        __syncthreads();
    }

    // epilogue: 32x32 C/D layout: col=lane&31, row=(reg&3)+8*(reg>>2)+4*(lane>>5)
#pragma unroll
    for (int j = 0; j < 2; j++) {
        const int col = bn + wn + j * 32 + l31;
        if (col < g.Nreal) {
            const float bv = g.bias[col];
#pragma unroll
            for (int i = 0; i < 2; i++) {
#pragma unroll
                for (int r = 0; r < 16; r++) {
                    const int row = bm + wm + i * 32 + (r & 3) + 8 * (r >> 2) + 4 * half;
                    float v = acc[i][j][r] + bv;
                    if (g.mode == 1) {
                        v = fmaxf(v, 0.f);
                        ushort h, l;
                        split1(v, h, l);
                        g.Ch[(size_t)row * g.ldc + col] = h;
                        g.Cl[(size_t)row * g.ldc + col] = l;
                    } else {
                        g.Cf[(size_t)row * g.ldc + col] = v;
                    }
                }
            }
        }
    }
}

// ------------- fused per-row softmax stats for both branches -------------
__global__ void softmax_stats2(const float* __restrict__ Zo, const float* __restrict__ Za,
                               const int* __restrict__ mc,
                               float* __restrict__ mxo, float* __restrict__ smo,
                               float* __restrict__ mxa, float* __restrict__ sma)
{
    const int r = blockIdx.x;
    if (r >= mc[0]) return;
    const float* Z; int ncols; float* mx; float* sm;
    if (blockIdx.y == 0) { Z = Zo; ncols = Oq; mx = mxo; sm = smo; }
    else                 { Z = Za; ncols = Aq; mx = mxa; sm = sma; }
    const float* row = Z + (size_t)r * ncols;
    __shared__ float red[256];
    float m = -INFINITY;
    for (int c = threadIdx.x; c < ncols; c += 256) m = fmaxf(m, row[c]);
    red[threadIdx.x] = m;
    __syncthreads();
    for (int s = 128; s > 0; s >>= 1) {
        if (threadIdx.x < s) red[threadIdx.x] = fmaxf(red[threadIdx.x], red[threadIdx.x + s]);
        __syncthreads();
    }
    m = red[0];
    __syncthreads();
    float su = 0.f;
    for (int c = threadIdx.x; c < ncols; c += 256) su += expf(row[c] - m);
    red[threadIdx.x] = su;
    __syncthreads();
    for (int s = 128; s > 0; s >>= 1) {
        if (threadIdx.x < s) red[threadIdx.x] += red[threadIdx.x + s];
        __syncthreads();
    }
    if (threadIdx.x == 0) { mx[r] = m; sm[r] = red[0]; }
}

// ------------- fused argmax + output gather (one block per label) -------------
__global__ void argmax_gather(
    const float* __restrict__ Zo, const float* __restrict__ Za,
    const float* __restrict__ mxo, const float* __restrict__ smo,
    const float* __restrict__ mxa, const float* __restrict__ sma,
    const int* __restrict__ label_img, const int* __restrict__ num_descs,
    const int* __restrict__ obj_labels, const int* __restrict__ att_labels,
    const int* __restrict__ off, float* __restrict__ out)
{
    const int l = blockIdx.x;
    const int b = label_img[l];
    const int nd = num_descs[b];
    const int r0 = off[b];
    const int t = threadIdx.x;           // 0..255

    __shared__ float ss[128];
    __shared__ int   si[128];
    if (t < 128) {
        float score = -INFINITY;
        if (t < Nq && t < nd) {
            const int r = r0 + t;
            const float po = expf(Zo[(size_t)r * Oq + obj_labels[l]] - mxo[r]) / smo[r];
            const float pa = expf(Za[(size_t)r * Aq + att_labels[l]] - mxa[r]) / sma[r];
            score = po * pa;
        }
        ss[t] = score;
        si[t] = t;
    }
    __syncthreads();
    for (int s = 64; s > 0; s >>= 1) {
        if (t < s) {
            const float s2 = ss[t + s];
            const int   i2 = si[t + s];
            // first-max tie-break; all -inf -> index 0
            if (s2 > ss[t] || (s2 == ss[t] && i2 < si[t])) { ss[t] = s2; si[t] = i2; }
        }
        __syncthreads();
    }
    const int r = r0 + si[0];

    const float mo = mxo[r], so = smo[r];
    const float* zo = Zo + (size_t)r * Oq;
    float* oo = out + (size_t)l * Oq;
    for (int c = t; c < Oq; c += 256)
        oo[c] = expf(zo[c] - mo) / so;

    const float ma = mxa[r], sa = sma[r];
    const float* za = Za + (size_t)r * Aq;
    float* oa = out + (size_t)Lq * Oq + (size_t)l * Aq;
    for (int c = t; c < Aq; c += 256)
        oa[c] = expf(za[c] - ma) / sa;
}

extern "C" void kernel_launch(void* const* d_in, const int* in_sizes, int n_in,
                              void* d_out, int out_size, void* d_ws, size_t ws_size,
                              hipStream_t stream)
{
    const float* x          = (const float*)d_in[0];
    const int*   num_descs  = (const int*)d_in[1];
    const int*   label_img  = (const int*)d_in[2];
    const int*   obj_labels = (const int*)d_in[3];
    const int*   att_labels = (const int*)d_in[4];
    const float* w1o = (const float*)d_in[5];  const float* b1o = (const float*)d_in[6];
    const float* w2o = (const float*)d_in[7];  const float* b2o = (const float*)d_in[8];
    const float* w3o = (const float*)d_in[9];  const float* b3o = (const float*)d_in[10];
    const float* w1a = (const float*)d_in[11]; const float* b1a = (const float*)d_in[12];
    const float* w2a = (const float*)d_in[13]; const float* b2a = (const float*)d_in[14];
    const float* w3a = (const float*)d_in[15]; const float* b3a = (const float*)d_in[16];
    float* out = (float*)d_out;

    // ---- workspace carve with lifetime-based aliasing ----
    char* p = (char*)d_ws;
    auto carve = [&](size_t bytes) { char* q = p; p += (bytes + 255) & ~(size_t)255; return q; };

    char* bufA = carve((size_t)Mq * Dq * 2 * 2);            // xh|xl -> h2{o,a}{h,l}
    char* bufB = carve((size_t)Mq * Hq * 2 * 2 * 2);        // h1{o,a}{h,l} -> z3o|z3a
    ushort* w1oth = (ushort*)carve((size_t)Hq * Dq * 2);  ushort* w1otl = (ushort*)carve((size_t)Hq * Dq * 2);
    ushort* w1ath = (ushort*)carve((size_t)Hq * Dq * 2);  ushort* w1atl = (ushort*)carve((size_t)Hq * Dq * 2);
    ushort* w2oth = (ushort*)carve((size_t)Hq * Hq * 2);  ushort* w2otl = (ushort*)carve((size_t)Hq * Hq * 2);
    ushort* w2ath = (ushort*)carve((size_t)Hq * Hq * 2);  ushort* w2atl = (ushort*)carve((size_t)Hq * Hq * 2);
    ushort* w3oth = (ushort*)carve((size_t)OqP * Hq * 2); ushort* w3otl = (ushort*)carve((size_t)OqP * Hq * 2);
    ushort* w3ath = (ushort*)carve((size_t)AqP * Hq * 2); ushort* w3atl = (ushort*)carve((size_t)AqP * Hq * 2);
    float* mxo = (float*)carve(Mq * 4); float* smo = (float*)carve(Mq * 4);
    float* mxa = (float*)carve(Mq * 4); float* sma = (float*)carve(Mq * 4);
    int* off    = (int*)carve(Bq * 4);
    int* mc     = (int*)carve(2 * 4);
    int* rowmap = (int*)carve(Mq * 4);

    // aliased views
    ushort* xh = (ushort*)bufA;
    ushort* xl = xh + (size_t)Mq * Dq;
    ushort* h2oh = (ushort*)bufA;                    // x dead after L1
    ushort* h2ol = h2oh + (size_t)Mq * Hq;
    ushort* h2ah = h2ol + (size_t)Mq * Hq;
    ushort* h2al = h2ah + (size_t)Mq * Hq;
    ushort* h1oh = (ushort*)bufB;
    ushort* h1ol = h1oh + (size_t)Mq * Hq;
    ushort* h1ah = h1ol + (size_t)Mq * Hq;
    ushort* h1al = h1ah + (size_t)Mq * Hq;
    float* z3o = (float*)bufB;                       // h1 dead after L2
    float* z3a = z3o + (size_t)Mq * Oq;

    // ---- preprocessing ----
    build_offsets<<<1, 128, 0, stream>>>(num_descs, off, mc, rowmap);
    split_compact<<<(int)((size_t)Mq * Dq / 8 / 256), 256, 0, stream>>>(x, rowmap, mc, xh, xl);

    {   // batched weight transpose+split: 6 segments, flat grid
        TSegs ts;
        int base = 0;
        auto seg = [&](const float* W, ushort* Th, ushort* Tl, int K, int N, int Npad) {
            TSeg s; s.W = W; s.Th = Th; s.Tl = Tl; s.K = K; s.N = N;
            s.gx = Npad / 32; s.base = base; base += (Npad / 32) * (K / 32); return s;
        };
        ts.s[0] = seg(w1o, w1oth, w1otl, Dq, Hq, Hq);
        ts.s[1] = seg(w1a, w1ath, w1atl, Dq, Hq, Hq);
        ts.s[2] = seg(w2o, w2oth, w2otl, Hq, Hq, Hq);
        ts.s[3] = seg(w2a, w2ath, w2atl, Hq, Hq, Hq);
        ts.s[4] = seg(w3o, w3oth, w3otl, Hq, Oq, OqP);
        ts.s[5] = seg(w3a, w3ath, w3atl, Hq, Aq, AqP);
        tsplit_all<<<base, 256, 0, stream>>>(ts);
    }

    // ---- L1: h1 = relu(x @ w1 + b1), both branches fused ----
    {
        GArgs go = { xh, xl, w1oth, w1otl, b1o, nullptr, h1oh, h1ol, Dq, Hq, Hq, Dq, Hq, 1 };
        GArgs ga = { xh, xl, w1ath, w1atl, b1a, nullptr, h1ah, h1al, Dq, Hq, Hq, Dq, Hq, 1 };
        gemm_split<<<dim3(Hq / 128, Mq / 128, 2), 256, 0, stream>>>(go, ga, mc);
    }
    // ---- L2: h2 = relu(h1 @ w2 + b2) ----
    {
        GArgs go = { h1oh, h1ol, w2oth, w2otl, b2o, nullptr, h2oh, h2ol, Hq, Hq, Hq, Hq, Hq, 1 };
        GArgs ga = { h1ah, h1al, w2ath, w2atl, b2a, nullptr, h2ah, h2al, Hq, Hq, Hq, Hq, Hq, 1 };
        gemm_split<<<dim3(Hq / 128, Mq / 128, 2), 256, 0, stream>>>(go, ga, mc);
    }
    // ---- L3: z3 = h2 @ w3 + b3 (fp32 out) ----
    {
        GArgs go = { h2oh, h2ol, w3oth, w3otl, b3o, z3o, nullptr, nullptr, Hq, OqP, Oq, Hq, Oq, 0 };
        GArgs ga = { h2ah, h2al, w3ath, w3atl, b3a, z3a, nullptr, nullptr, Hq, AqP, Aq, Hq, Aq, 0 };
        gemm_split<<<dim3(OqP / 128, Mq / 128, 2), 256, 0, stream>>>(go, ga, mc);
    }

    // ---- epilogue ----
    softmax_stats2<<<dim3(Mq, 2), 256, 0, stream>>>(z3o, z3a, mc, mxo, smo, mxa, sma);
    argmax_gather<<<Lq, 256, 0, stream>>>(z3o, z3a, mxo, smo, mxa, sma,
                                          label_img, num_descs, obj_labels, att_labels, off, out);
}